// Round 10
// baseline (257.425 us; speedup 1.0000x reference)
//
#include <hip/hip_runtime.h>
#include <float.h>
#include <stdint.h>

// Problem constants: B=64, H=W=32, C=256, D=H*W=1024, K=1024
#define B_   64
#define C_   256
#define D_   1024
#define K_   1024
#define M_   16384
#define NX_  16777216          // B*D*C = M*D
#define DISC_OFF NX_
#define LOSS_OFF (NX_ + M_)

typedef _Float16 h8 __attribute__((ext_vector_type(8)));
typedef float    f4 __attribute__((ext_vector_type(4)));

// Power-of-2 split scales (exact). acc = 2^20 * dot.
#define XSCALE 512.0f
#define ESCALE 2048.0f
#define DOT_UNSCALE_2 (2.0f / 1048576.0f)

// d_ws layout (float offsets).
#define WS_EH  0          // 1M fp16 = 524288 floats
#define WS_EL  524288
#define WS_CN  1048576    // 1024
#define WS_PCN 1049600    // 128*1024 = 131072
#define WS_PM  1180672    // 16384 u64 = 32768 floats

__device__ __forceinline__ void async16(const _Float16* g, _Float16* l) {
    __builtin_amdgcn_global_load_lds(
        (const __attribute__((address_space(1))) unsigned int*)g,
        (__attribute__((address_space(3))) unsigned int*)l, 16, 0, 0);
}

// ---------------------------------------------------------------------------
// E split only (X split is fused into the GEMM's A-staging path).
// 128 blocks: block = one k-octet o; thread = 4 consecutive n (16B loads).
// ---------------------------------------------------------------------------
__global__ __launch_bounds__(256) void esplit_kernel(const float* __restrict__ E,
                                                     _Float16* __restrict__ Eh,
                                                     _Float16* __restrict__ El,
                                                     float* __restrict__ pcn) {
    const int t  = threadIdx.x;
    const int o  = blockIdx.x;     // k-octet [0,128)
    const int d0 = o * 8;
    const int n0 = t * 4;          // 4 consecutive columns
    float4 row[8];
    #pragma unroll
    for (int i = 0; i < 8; ++i)
        row[i] = *(const float4*)(E + (size_t)(d0 + i) * K_ + n0);
    float s0 = 0.f, s1 = 0.f, s2 = 0.f, s3 = 0.f;
    h8 hh[4], ll[4];
    #pragma unroll
    for (int i = 0; i < 8; ++i) {
        const float* rp = (const float*)&row[i];
        #pragma unroll
        for (int j = 0; j < 4; ++j) {
            const float v  = rp[j];
            const float vs = v * ESCALE;
            const _Float16 h = (_Float16)vs;
            hh[j][i] = h;
            ll[j][i] = (_Float16)(vs - (float)h);
        }
        s0 = fmaf(rp[0], rp[0], s0);
        s1 = fmaf(rp[1], rp[1], s1);
        s2 = fmaf(rp[2], rp[2], s2);
        s3 = fmaf(rp[3], rp[3], s3);
    }
    float4 sv; sv.x = s0; sv.y = s1; sv.z = s2; sv.w = s3;
    *(float4*)(pcn + o * K_ + n0) = sv;
    const int nt    = n0 >> 4;
    const int kt    = o >> 2;
    const int lane0 = (n0 & 15) + (o & 3) * 16;
    const size_t base = ((size_t)(nt * 32 + kt) * 64 + lane0) * 8;
    #pragma unroll
    for (int j = 0; j < 4; ++j) {
        *(h8*)(Eh + base + (size_t)j * 8) = hh[j];
        *(h8*)(El + base + (size_t)j * 8) = ll[j];
    }
}

// colnorm: sum the 128 partials per column; init pM to +inf; zero loss.
__global__ __launch_bounds__(256) void colnorm2_kernel(const float* __restrict__ pcn,
                                                       float* __restrict__ cn,
                                                       unsigned long long* __restrict__ pM,
                                                       float* __restrict__ loss_slot) {
    __shared__ float sp[4][64];
    const int t    = threadIdx.x;
    const int col  = blockIdx.x * 64 + (t & 63);
    const int part = t >> 6;
    float s = 0.f;
    #pragma unroll 8
    for (int i = 0; i < 32; ++i) s += pcn[(part * 32 + i) * K_ + col];
    sp[part][t & 63] = s;
    const int gid = blockIdx.x * 256 + t;          // 0..4095
    #pragma unroll
    for (int i = 0; i < 4; ++i) pM[gid * 4 + i] = 0xFFFFFFFFFFFFFFFFull;
    __syncthreads();
    if (t < 64) cn[col] = (sp[0][t] + sp[1][t]) + (sp[2][t] + sp[3][t]);
    if (blockIdx.x == 0 && t == 0) *loss_slot = 0.0f;
}

// ---------------------------------------------------------------------------
// Split-fp16 MFMA distance GEMM + global argmin via packed atomicMin.
// FUSED X split v4: R9's 2-step-lead reg-staged A conversion, but WITHOUT
// the sched_barrier(0) wall — the 2-step lead alone guarantees >= 1 full
// step (~3700 cyc) of load cover even if the compiler sinks the issue, and
// removing the wall lets MFMAs interleave with staging issue (m141 lesson).
// Epilogue: per-row packed (flipped-float-bits<<32 | col) atomicMin into
// pM[row] — monotone in v, ties -> lowest index (numpy semantics), replaces
// the pV/pI partials + reduce kernel.
// LDS: B 2x32KB + FRAG 2x16KB + 4KB epilogue = 100 KB (1 block/CU).
// Grid 512 = 128 rt x 4 ct; default dispatch gives each XCD one ct (period
// 8 vs 4) -> B panel 1 MB/XCD L2-resident.
// ---------------------------------------------------------------------------
__global__ __launch_bounds__(512, 2) void gemm_argmin_kernel(
        const float* __restrict__ x,
        const _Float16* __restrict__ Eh, const _Float16* __restrict__ El,
        const float* __restrict__ cn,
        unsigned long long* __restrict__ pM) {
    extern __shared__ _Float16 smem[];   // 51200 fp16 = 100 KB
    // layout (fp16 offsets): B0 @0, B1 @16384, FRAG0 @32768 (hi 4096|lo 4096),
    //                        FRAG1 @40960, cV/cI @49152 (4 KB)

    const int t    = threadIdx.x;
    const int rt   = blockIdx.x >> 2;     // 0..127
    const int ct   = blockIdx.x & 3;      // 0..3
    const int wave = t >> 6, lane = t & 63;
    const int lo16 = lane & 15, hi4 = lane >> 4;
    const int mq   = (wave & 1) * 64;
    const int nq   = (wave >> 1) * 64;    // 0,64,128,192
    const int nt0  = ct * 16;
    const int n0g  = ct * 256;

    // ---- B staging: 32 async chunk-loads per k-step, 4 per wave ----
    const _Float16* srcB[4];
    int offB[4];
    #pragma unroll
    for (int i = 0; i < 4; ++i) {
        const int id = wave * 4 + i;          // 0..31
        const int plane = id >> 4, nt = id & 15;
        srcB[i] = (plane ? El : Eh) + ((size_t)(nt0 + nt) * 32) * 512 + lane * 8;
        offB[i] = (plane * 16 + nt) * 512 + lane * 8;
    }
    auto stageB = [&](int s) {
        _Float16* bbuf = smem + (s & 1) * 16384;
        #pragma unroll
        for (int i = 0; i < 4; ++i)
            async16(srcB[i] + (size_t)s * 512, bbuf + offB[i]);
    };

    // ---- A reg-staged fused split: thread owns (row cl, k-octet ko8) ----
    const int b   = rt >> 1;
    const int c0  = (rt & 1) * 128;
    const int cl  = t & 127;              // m-row within tile
    const int ko8 = t >> 7;               // local k-octet 0..3
    const float* xA = x + ((size_t)(b * 1024 + ko8 * 8)) * 256 + c0 + cl;
    const int fwr = (cl >> 4) * 512 + ((cl & 15) + ko8 * 16) * 8;

    float av[8];
    auto loadA = [&](int s) {             // data for step s -> av
        #pragma unroll
        for (int j = 0; j < 8; ++j)
            av[j] = xA[((size_t)(s * 32) + j) * 256];
    };
    auto writeA = [&](int s) {            // av -> FRAG[s&1] (bit-exact split)
        _Float16* fb = smem + 32768 + (s & 1) * 8192;
        h8 hh, ll;
        #pragma unroll
        for (int j = 0; j < 8; ++j) {
            const float vs = av[j] * XSCALE;
            const _Float16 h = (_Float16)vs;
            hh[j] = h;
            ll[j] = (_Float16)(vs - (float)h);
        }
        *(h8*)(fb + fwr) = hh;
        *(h8*)(fb + 4096 + fwr) = ll;
    };

    f4 acc[4][4];
    const f4 zero = {0.f, 0.f, 0.f, 0.f};
    #pragma unroll
    for (int i = 0; i < 4; ++i)
        #pragma unroll
        for (int j = 0; j < 4; ++j) acc[i][j] = zero;

    // ---- prologue: FRAG0 written, av holds step-1 data, B0 in flight ----
    loadA(0);
    writeA(0);
    loadA(1);
    stageB(0);

    for (int s = 0; s < 32; ++s) {
        __syncthreads();   // drains vmcnt (B(s)) + lgkm (FRAG(s) writes); barrier
        if (s + 1 < 32) {
            stageB(s + 1);
            writeA(s + 1);                 // av = data(s+1); consumed here
        }
        if (s + 2 < 32) loadA(s + 2);      // issued now, consumed next step
        // (no sched_barrier: 2-step lead tolerates sinking; MFMA may interleave)

        const _Float16* Abuf = smem + 32768 + (s & 1) * 8192;
        const _Float16* Bbuf = smem + (s & 1) * 16384;
        h8 Bf[2][4];
        #pragma unroll
        for (int tn = 0; tn < 4; ++tn) {
            const int tixn = (nq >> 4) + tn;
            Bf[0][tn] = *(const h8*)&Bbuf[tixn * 512 + lane * 8];
            Bf[1][tn] = *(const h8*)&Bbuf[(16 + tixn) * 512 + lane * 8];
        }
        #pragma unroll
        for (int tm = 0; tm < 4; ++tm) {
            const int tixm = (mq >> 4) + tm;
            const h8 Ah = *(const h8*)&Abuf[tixm * 512 + lane * 8];
            const h8 Al = *(const h8*)&Abuf[4096 + tixm * 512 + lane * 8];
            #pragma unroll
            for (int tn = 0; tn < 4; ++tn) {
                acc[tm][tn] = __builtin_amdgcn_mfma_f32_16x16x32_f16(Ah, Bf[0][tn], acc[tm][tn], 0, 0, 0);
                acc[tm][tn] = __builtin_amdgcn_mfma_f32_16x16x32_f16(Ah, Bf[1][tn], acc[tm][tn], 0, 0, 0);
                acc[tm][tn] = __builtin_amdgcn_mfma_f32_16x16x32_f16(Al, Bf[0][tn], acc[tm][tn], 0, 0, 0);
            }
        }
    }

    // ---- epilogue: per-row argmin over this block's 256 cols ----
    __syncthreads();
    float* cV = (float*)(smem + 49152);   // [128][4]
    int*   cI = (int*)(cV + 512);         // [128][4]

    float cnv[4];
    #pragma unroll
    for (int tn = 0; tn < 4; ++tn) cnv[tn] = cn[n0g + nq + tn * 16 + lo16];

    #pragma unroll
    for (int tm = 0; tm < 4; ++tm) {
        #pragma unroll
        for (int r = 0; r < 4; ++r) {
            float bv = FLT_MAX;
            int   bi = 0;
            #pragma unroll
            for (int tn = 0; tn < 4; ++tn) {   // ascending col => first-index tie-break
                const float v = cnv[tn] - acc[tm][tn][r] * DOT_UNSCALE_2;
                if (v < bv) { bv = v; bi = nq + tn * 16 + lo16; }
            }
            #pragma unroll
            for (int msk = 1; msk < 16; msk <<= 1) {
                const float ov = __shfl_xor(bv, msk, 64);
                const int   oi = __shfl_xor(bi, msk, 64);
                if (ov < bv || (ov == bv && oi < bi)) { bv = ov; bi = oi; }
            }
            if (lo16 == 0) {
                const int row = mq + tm * 16 + hi4 * 4 + r;
                const int g   = wave >> 1;     // n-quadrant index (ascending n)
                cV[row * 4 + g] = bv;
                cI[row * 4 + g] = bi;
            }
        }
    }
    __syncthreads();
    if (t < 128) {
        float bv = FLT_MAX;
        int   bi = 0;
        #pragma unroll
        for (int g = 0; g < 4; ++g) {          // ascending n-base, strict <
            const float v = cV[t * 4 + g];
            const int   i = cI[t * 4 + g];
            if (v < bv || (v == bv && i < bi)) { bv = v; bi = i; }
        }
        // pack: order-flipped float bits | global col. atomicMin => min v,
        // tie -> lowest index (matches numpy argmin first-min semantics).
        const unsigned int u   = __float_as_uint(bv);
        const unsigned int key = u ^ ((u & 0x80000000u) ? 0xFFFFFFFFu : 0x80000000u);
        const unsigned long long packed =
            ((unsigned long long)key << 32) | (unsigned int)(n0g + bi);
        atomicMin(&pM[rt * 128 + t], packed);
    }
}

// ---------------------------------------------------------------------------
// finalize: one block per d. E row d staged in LDS (4 KB); gather indices
// decoded from packed pM. Block d also writes disc[16d..16d+16).
// q = x + (e - x); loss += 1.25*mean((x-e)^2). Fully coalesced x/q streams.
// ---------------------------------------------------------------------------
__global__ __launch_bounds__(256) void finalize_kernel(const float* __restrict__ x,
                                                       const float* __restrict__ E,
                                                       const unsigned long long* __restrict__ pM,
                                                       float* __restrict__ disc,
                                                       float* __restrict__ out,
                                                       float* __restrict__ loss) {
    __shared__ float Erow[1024];
    const int t = threadIdx.x;
    const int d = blockIdx.x;
    *(float4*)&Erow[t * 4] = *(const float4*)(E + (size_t)d * K_ + t * 4);
    if (t < 16)
        disc[d * 16 + t] = (float)(unsigned int)(pM[d * 16 + t] & 0xFFFFFFFFull);
    __syncthreads();

    const int bl = t >> 6;           // wave id -> b offset
    const int c4 = (t & 63) * 4;
    float lsum = 0.f;
    #pragma unroll 4
    for (int bg = 0; bg < 64; bg += 4) {
        const int b = bg + bl;
        const unsigned long long* pp = pM + b * 256 + c4;
        const int i0 = (unsigned int)(pp[0] & 0xFFFFFFFFull);
        const int i1 = (unsigned int)(pp[1] & 0xFFFFFFFFull);
        const int i2 = (unsigned int)(pp[2] & 0xFFFFFFFFull);
        const int i3 = (unsigned int)(pp[3] & 0xFFFFFFFFull);
        const size_t xoff = ((size_t)(b * 1024 + d) << 8) + c4;
        const float4 xv = *(const float4*)(x + xoff);
        const float e0 = Erow[i0];
        const float e1 = Erow[i1];
        const float e2 = Erow[i2];
        const float e3 = Erow[i3];
        float4 qv;
        qv.x = xv.x + (e0 - xv.x);
        qv.y = xv.y + (e1 - xv.y);
        qv.z = xv.z + (e2 - xv.z);
        qv.w = xv.w + (e3 - xv.w);
        *(float4*)(out + xoff) = qv;
        const float d0 = xv.x - e0, d1 = xv.y - e1, d2 = xv.z - e2, d3 = xv.w - e3;
        lsum += fmaf(d0, d0, fmaf(d1, d1, fmaf(d2, d2, d3 * d3)));
    }

    #pragma unroll
    for (int off = 32; off > 0; off >>= 1)
        lsum += __shfl_down(lsum, off);
    __shared__ float wsum[4];
    if ((t & 63) == 0) wsum[t >> 6] = lsum;
    __syncthreads();
    if (t == 0) {
        const float s = (wsum[0] + wsum[1]) + (wsum[2] + wsum[3]);
        atomicAdd(loss, s * (1.25f / 16777216.0f));
    }
}

// ---------------------------------------------------------------------------
extern "C" void kernel_launch(void* const* d_in, const int* in_sizes, int n_in,
                              void* d_out, int out_size, void* d_ws, size_t ws_size,
                              hipStream_t stream) {
    (void)in_sizes; (void)n_in; (void)out_size; (void)ws_size;
    const float* x = (const float*)d_in[0];   // (64,32,32,256) f32
    const float* E = (const float*)d_in[1];   // (1024,1024)    f32
    float* out = (float*)d_out;
    float* ws  = (float*)d_ws;

    _Float16* Eh = (_Float16*)(ws + WS_EH);
    _Float16* El = (_Float16*)(ws + WS_EL);
    float* cn    = ws + WS_CN;
    float* pcn   = ws + WS_PCN;
    unsigned long long* pM = (unsigned long long*)(ws + WS_PM);

    float* disc  = out + DISC_OFF;
    float* loss  = out + LOSS_OFF;

    // Allow 100 KB dynamic LDS (default cap is 64 KB; gfx950 WG limit 160 KB).
    (void)hipFuncSetAttribute((const void*)gemm_argmin_kernel,
                              hipFuncAttributeMaxDynamicSharedMemorySize, 102400);

    esplit_kernel  <<<128,  256, 0, stream>>>(E, Eh, El, pcn);
    colnorm2_kernel<<<16,   256, 0, stream>>>(pcn, cn, pM, loss);
    gemm_argmin_kernel<<<512, 512, 102400, stream>>>(x, Eh, El, cn, pM);
    finalize_kernel<<<1024, 256, 0, stream>>>(x, E, pM, disc, out, loss);
}

// Round 11
// 233.154 us; speedup vs baseline: 1.1041x; 1.1041x over previous
//
#include <hip/hip_runtime.h>
#include <float.h>
#include <stdint.h>

// Problem constants: B=64, H=W=32, C=256, D=H*W=1024, K=1024
#define B_   64
#define C_   256
#define D_   1024
#define K_   1024
#define M_   16384
#define NX_  16777216          // B*D*C = M*D
#define DISC_OFF NX_
#define LOSS_OFF (NX_ + M_)

typedef _Float16 h8 __attribute__((ext_vector_type(8)));
typedef float    f4 __attribute__((ext_vector_type(4)));

// Power-of-2 split scales (exact). acc = 2^20 * dot.
#define XSCALE 512.0f
#define ESCALE 2048.0f
#define DOT_UNSCALE_2 (2.0f / 1048576.0f)

// d_ws layout (float offsets).
#define WS_EH  0          // 1M fp16 = 524288 floats
#define WS_EL  524288
#define WS_CN  1048576    // 1024
#define WS_PCN 1049600    // 128*1024 = 131072
#define WS_PM  1180672    // 16384 u64 = 32768 floats

__device__ __forceinline__ void async16(const _Float16* g, _Float16* l) {
    __builtin_amdgcn_global_load_lds(
        (const __attribute__((address_space(1))) unsigned int*)g,
        (__attribute__((address_space(3))) unsigned int*)l, 16, 0, 0);
}

// ---------------------------------------------------------------------------
// E split only (X split is fused into the GEMM's A-staging path).
// 128 blocks: block = one k-octet o; thread = 4 consecutive n (16B loads).
// ---------------------------------------------------------------------------
__global__ __launch_bounds__(256) void esplit_kernel(const float* __restrict__ E,
                                                     _Float16* __restrict__ Eh,
                                                     _Float16* __restrict__ El,
                                                     float* __restrict__ pcn) {
    const int t  = threadIdx.x;
    const int o  = blockIdx.x;     // k-octet [0,128)
    const int d0 = o * 8;
    const int n0 = t * 4;          // 4 consecutive columns
    float4 row[8];
    #pragma unroll
    for (int i = 0; i < 8; ++i)
        row[i] = *(const float4*)(E + (size_t)(d0 + i) * K_ + n0);
    float s0 = 0.f, s1 = 0.f, s2 = 0.f, s3 = 0.f;
    h8 hh[4], ll[4];
    #pragma unroll
    for (int i = 0; i < 8; ++i) {
        const float* rp = (const float*)&row[i];
        #pragma unroll
        for (int j = 0; j < 4; ++j) {
            const float v  = rp[j];
            const float vs = v * ESCALE;
            const _Float16 h = (_Float16)vs;
            hh[j][i] = h;
            ll[j][i] = (_Float16)(vs - (float)h);
        }
        s0 = fmaf(rp[0], rp[0], s0);
        s1 = fmaf(rp[1], rp[1], s1);
        s2 = fmaf(rp[2], rp[2], s2);
        s3 = fmaf(rp[3], rp[3], s3);
    }
    float4 sv; sv.x = s0; sv.y = s1; sv.z = s2; sv.w = s3;
    *(float4*)(pcn + o * K_ + n0) = sv;
    const int nt    = n0 >> 4;
    const int kt    = o >> 2;
    const int lane0 = (n0 & 15) + (o & 3) * 16;
    const size_t base = ((size_t)(nt * 32 + kt) * 64 + lane0) * 8;
    #pragma unroll
    for (int j = 0; j < 4; ++j) {
        *(h8*)(Eh + base + (size_t)j * 8) = hh[j];
        *(h8*)(El + base + (size_t)j * 8) = ll[j];
    }
}

// colnorm: sum the 128 partials per column; init pM to +inf; zero loss.
__global__ __launch_bounds__(256) void colnorm2_kernel(const float* __restrict__ pcn,
                                                       float* __restrict__ cn,
                                                       unsigned long long* __restrict__ pM,
                                                       float* __restrict__ loss_slot) {
    __shared__ float sp[4][64];
    const int t    = threadIdx.x;
    const int col  = blockIdx.x * 64 + (t & 63);
    const int part = t >> 6;
    float s = 0.f;
    #pragma unroll 8
    for (int i = 0; i < 32; ++i) s += pcn[(part * 32 + i) * K_ + col];
    sp[part][t & 63] = s;
    const int gid = blockIdx.x * 256 + t;          // 0..4095
    #pragma unroll
    for (int i = 0; i < 4; ++i) pM[gid * 4 + i] = 0xFFFFFFFFFFFFFFFFull;
    __syncthreads();
    if (t < 64) cn[col] = (sp[0][t] + sp[1][t]) + (sp[2][t] + sp[3][t]);
    if (blockIdx.x == 0 && t == 0) *loss_slot = 0.0f;
}

// ---------------------------------------------------------------------------
// Split-fp16 MFMA distance GEMM + global argmin via packed atomicMin.
// FUSED X split v3 loop (R9-exact, including the sched_barrier(0) wall —
// A/B across R9/R10 showed the wall is load-bearing: removing it cost
// +25 us of pure main-loop stall, MfmaUtil 37->30.5 at constant MFMA work).
//   at step s: [barrier] -> stageB(s+1) async -> ds_write av (data s+1) into
//   FRAG[(s+1)&1] -> issue 8 scalar x-loads for step s+2 into av ->
//   sched_barrier(0) -> ds_read frags -> 48 MFMA.
// Epilogue: per-row packed (flipped-float-bits<<32 | col) atomicMin into
// pM[row] — monotone in v, ties -> lowest index (numpy semantics), replaces
// the pV/pI partials + reduce kernel (R10's launch-count win, kept).
// LDS: B 2x32KB + FRAG 2x16KB + 4KB epilogue = 100 KB (1 block/CU).
// Grid 512 = 128 rt x 4 ct.
// ---------------------------------------------------------------------------
__global__ __launch_bounds__(512, 2) void gemm_argmin_kernel(
        const float* __restrict__ x,
        const _Float16* __restrict__ Eh, const _Float16* __restrict__ El,
        const float* __restrict__ cn,
        unsigned long long* __restrict__ pM) {
    extern __shared__ _Float16 smem[];   // 51200 fp16 = 100 KB
    // layout (fp16 offsets): B0 @0, B1 @16384, FRAG0 @32768 (hi 4096|lo 4096),
    //                        FRAG1 @40960, cV/cI @49152 (4 KB)

    const int t    = threadIdx.x;
    const int rt   = blockIdx.x >> 2;     // 0..127
    const int ct   = blockIdx.x & 3;      // 0..3
    const int wave = t >> 6, lane = t & 63;
    const int lo16 = lane & 15, hi4 = lane >> 4;
    const int mq   = (wave & 1) * 64;
    const int nq   = (wave >> 1) * 64;    // 0,64,128,192
    const int nt0  = ct * 16;
    const int n0g  = ct * 256;

    // ---- B staging: 32 async chunk-loads per k-step, 4 per wave ----
    const _Float16* srcB[4];
    int offB[4];
    #pragma unroll
    for (int i = 0; i < 4; ++i) {
        const int id = wave * 4 + i;          // 0..31
        const int plane = id >> 4, nt = id & 15;
        srcB[i] = (plane ? El : Eh) + ((size_t)(nt0 + nt) * 32) * 512 + lane * 8;
        offB[i] = (plane * 16 + nt) * 512 + lane * 8;
    }
    auto stageB = [&](int s) {
        _Float16* bbuf = smem + (s & 1) * 16384;
        #pragma unroll
        for (int i = 0; i < 4; ++i)
            async16(srcB[i] + (size_t)s * 512, bbuf + offB[i]);
    };

    // ---- A reg-staged fused split: thread owns (row cl, k-octet ko8) ----
    const int b   = rt >> 1;
    const int c0  = (rt & 1) * 128;
    const int cl  = t & 127;              // m-row within tile
    const int ko8 = t >> 7;               // local k-octet 0..3
    const float* xA = x + ((size_t)(b * 1024 + ko8 * 8)) * 256 + c0 + cl;
    const int fwr = (cl >> 4) * 512 + ((cl & 15) + ko8 * 16) * 8;

    float av[8];
    auto loadA = [&](int s) {             // data for step s -> av
        #pragma unroll
        for (int j = 0; j < 8; ++j)
            av[j] = xA[((size_t)(s * 32) + j) * 256];
    };
    auto writeA = [&](int s) {            // av -> FRAG[s&1] (bit-exact split)
        _Float16* fb = smem + 32768 + (s & 1) * 8192;
        h8 hh, ll;
        #pragma unroll
        for (int j = 0; j < 8; ++j) {
            const float vs = av[j] * XSCALE;
            const _Float16 h = (_Float16)vs;
            hh[j] = h;
            ll[j] = (_Float16)(vs - (float)h);
        }
        *(h8*)(fb + fwr) = hh;
        *(h8*)(fb + 4096 + fwr) = ll;
    };

    f4 acc[4][4];
    const f4 zero = {0.f, 0.f, 0.f, 0.f};
    #pragma unroll
    for (int i = 0; i < 4; ++i)
        #pragma unroll
        for (int j = 0; j < 4; ++j) acc[i][j] = zero;

    // ---- prologue: FRAG0 written, av holds step-1 data, B0 in flight ----
    loadA(0);
    writeA(0);
    loadA(1);
    stageB(0);

    for (int s = 0; s < 32; ++s) {
        __syncthreads();   // drains vmcnt (B(s)) + lgkm (FRAG(s) writes); barrier
        if (s + 1 < 32) {
            stageB(s + 1);
            writeA(s + 1);                 // av = data(s+1); consumed here
        }
        if (s + 2 < 32) loadA(s + 2);      // issued now, consumed next step
        __builtin_amdgcn_sched_barrier(0); // pin load issue before MFMA cluster

        const _Float16* Abuf = smem + 32768 + (s & 1) * 8192;
        const _Float16* Bbuf = smem + (s & 1) * 16384;
        h8 Bf[2][4];
        #pragma unroll
        for (int tn = 0; tn < 4; ++tn) {
            const int tixn = (nq >> 4) + tn;
            Bf[0][tn] = *(const h8*)&Bbuf[tixn * 512 + lane * 8];
            Bf[1][tn] = *(const h8*)&Bbuf[(16 + tixn) * 512 + lane * 8];
        }
        #pragma unroll
        for (int tm = 0; tm < 4; ++tm) {
            const int tixm = (mq >> 4) + tm;
            const h8 Ah = *(const h8*)&Abuf[tixm * 512 + lane * 8];
            const h8 Al = *(const h8*)&Abuf[4096 + tixm * 512 + lane * 8];
            #pragma unroll
            for (int tn = 0; tn < 4; ++tn) {
                acc[tm][tn] = __builtin_amdgcn_mfma_f32_16x16x32_f16(Ah, Bf[0][tn], acc[tm][tn], 0, 0, 0);
                acc[tm][tn] = __builtin_amdgcn_mfma_f32_16x16x32_f16(Ah, Bf[1][tn], acc[tm][tn], 0, 0, 0);
                acc[tm][tn] = __builtin_amdgcn_mfma_f32_16x16x32_f16(Al, Bf[0][tn], acc[tm][tn], 0, 0, 0);
            }
        }
    }

    // ---- epilogue: per-row argmin over this block's 256 cols ----
    __syncthreads();
    float* cV = (float*)(smem + 49152);   // [128][4]
    int*   cI = (int*)(cV + 512);         // [128][4]

    float cnv[4];
    #pragma unroll
    for (int tn = 0; tn < 4; ++tn) cnv[tn] = cn[n0g + nq + tn * 16 + lo16];

    #pragma unroll
    for (int tm = 0; tm < 4; ++tm) {
        #pragma unroll
        for (int r = 0; r < 4; ++r) {
            float bv = FLT_MAX;
            int   bi = 0;
            #pragma unroll
            for (int tn = 0; tn < 4; ++tn) {   // ascending col => first-index tie-break
                const float v = cnv[tn] - acc[tm][tn][r] * DOT_UNSCALE_2;
                if (v < bv) { bv = v; bi = nq + tn * 16 + lo16; }
            }
            #pragma unroll
            for (int msk = 1; msk < 16; msk <<= 1) {
                const float ov = __shfl_xor(bv, msk, 64);
                const int   oi = __shfl_xor(bi, msk, 64);
                if (ov < bv || (ov == bv && oi < bi)) { bv = ov; bi = oi; }
            }
            if (lo16 == 0) {
                const int row = mq + tm * 16 + hi4 * 4 + r;
                const int g   = wave >> 1;     // n-quadrant index (ascending n)
                cV[row * 4 + g] = bv;
                cI[row * 4 + g] = bi;
            }
        }
    }
    __syncthreads();
    if (t < 128) {
        float bv = FLT_MAX;
        int   bi = 0;
        #pragma unroll
        for (int g = 0; g < 4; ++g) {          // ascending n-base, strict <
            const float v = cV[t * 4 + g];
            const int   i = cI[t * 4 + g];
            if (v < bv || (v == bv && i < bi)) { bv = v; bi = i; }
        }
        // pack: order-flipped float bits | global col. atomicMin => min v,
        // tie -> lowest index (matches numpy argmin first-min semantics).
        const unsigned int u   = __float_as_uint(bv);
        const unsigned int key = u ^ ((u & 0x80000000u) ? 0xFFFFFFFFu : 0x80000000u);
        const unsigned long long packed =
            ((unsigned long long)key << 32) | (unsigned int)(n0g + bi);
        atomicMin(&pM[rt * 128 + t], packed);
    }
}

// ---------------------------------------------------------------------------
// finalize: one block per d. E row d staged in LDS (4 KB); gather indices
// decoded from packed pM. Block d also writes disc[16d..16d+16).
// q = x + (e - x); loss += 1.25*mean((x-e)^2). Fully coalesced x/q streams.
// ---------------------------------------------------------------------------
__global__ __launch_bounds__(256) void finalize_kernel(const float* __restrict__ x,
                                                       const float* __restrict__ E,
                                                       const unsigned long long* __restrict__ pM,
                                                       float* __restrict__ disc,
                                                       float* __restrict__ out,
                                                       float* __restrict__ loss) {
    __shared__ float Erow[1024];
    const int t = threadIdx.x;
    const int d = blockIdx.x;
    *(float4*)&Erow[t * 4] = *(const float4*)(E + (size_t)d * K_ + t * 4);
    if (t < 16)
        disc[d * 16 + t] = (float)(unsigned int)(pM[d * 16 + t] & 0xFFFFFFFFull);
    __syncthreads();

    const int bl = t >> 6;           // wave id -> b offset
    const int c4 = (t & 63) * 4;
    float lsum = 0.f;
    #pragma unroll 4
    for (int bg = 0; bg < 64; bg += 4) {
        const int b = bg + bl;
        const unsigned long long* pp = pM + b * 256 + c4;
        const int i0 = (unsigned int)(pp[0] & 0xFFFFFFFFull);
        const int i1 = (unsigned int)(pp[1] & 0xFFFFFFFFull);
        const int i2 = (unsigned int)(pp[2] & 0xFFFFFFFFull);
        const int i3 = (unsigned int)(pp[3] & 0xFFFFFFFFull);
        const size_t xoff = ((size_t)(b * 1024 + d) << 8) + c4;
        const float4 xv = *(const float4*)(x + xoff);
        const float e0 = Erow[i0];
        const float e1 = Erow[i1];
        const float e2 = Erow[i2];
        const float e3 = Erow[i3];
        float4 qv;
        qv.x = xv.x + (e0 - xv.x);
        qv.y = xv.y + (e1 - xv.y);
        qv.z = xv.z + (e2 - xv.z);
        qv.w = xv.w + (e3 - xv.w);
        *(float4*)(out + xoff) = qv;
        const float d0 = xv.x - e0, d1 = xv.y - e1, d2 = xv.z - e2, d3 = xv.w - e3;
        lsum += fmaf(d0, d0, fmaf(d1, d1, fmaf(d2, d2, d3 * d3)));
    }

    #pragma unroll
    for (int off = 32; off > 0; off >>= 1)
        lsum += __shfl_down(lsum, off);
    __shared__ float wsum[4];
    if ((t & 63) == 0) wsum[t >> 6] = lsum;
    __syncthreads();
    if (t == 0) {
        const float s = (wsum[0] + wsum[1]) + (wsum[2] + wsum[3]);
        atomicAdd(loss, s * (1.25f / 16777216.0f));
    }
}

// ---------------------------------------------------------------------------
extern "C" void kernel_launch(void* const* d_in, const int* in_sizes, int n_in,
                              void* d_out, int out_size, void* d_ws, size_t ws_size,
                              hipStream_t stream) {
    (void)in_sizes; (void)n_in; (void)out_size; (void)ws_size;
    const float* x = (const float*)d_in[0];   // (64,32,32,256) f32
    const float* E = (const float*)d_in[1];   // (1024,1024)    f32
    float* out = (float*)d_out;
    float* ws  = (float*)d_ws;

    _Float16* Eh = (_Float16*)(ws + WS_EH);
    _Float16* El = (_Float16*)(ws + WS_EL);
    float* cn    = ws + WS_CN;
    float* pcn   = ws + WS_PCN;
    unsigned long long* pM = (unsigned long long*)(ws + WS_PM);

    float* disc  = out + DISC_OFF;
    float* loss  = out + LOSS_OFF;

    // Allow 100 KB dynamic LDS (default cap is 64 KB; gfx950 WG limit 160 KB).
    (void)hipFuncSetAttribute((const void*)gemm_argmin_kernel,
                              hipFuncAttributeMaxDynamicSharedMemorySize, 102400);

    esplit_kernel  <<<128,  256, 0, stream>>>(E, Eh, El, pcn);
    colnorm2_kernel<<<16,   256, 0, stream>>>(pcn, cn, pM, loss);
    gemm_argmin_kernel<<<512, 512, 102400, stream>>>(x, Eh, El, cn, pM);
    finalize_kernel<<<1024, 256, 0, stream>>>(x, E, pM, disc, out, loss);
}